// Round 1
// baseline (742.453 us; speedup 1.0000x reference)
//
#include <hip/hip_runtime.h>
#include <hip/hip_fp16.h>
#include <stdint.h>

#define N_NODES_C 100000
#define N_PAIRS_C 1600000
#define FDIM 64
#define HH 4
#define DD 16

typedef float vf4 __attribute__((ext_vector_type(4)));

// ---------------- Phase 1: per-head QKV projection (+ fused out-zeroing) ----
// One thread per (n, h). q table stays fp32 (read rarely, sequentially).
// k,v packed into ONE fp16 table, element-interleaved: kv[n][e*2+0]=k_e,
// kv[n][e*2+1]=v_e  -> pair-phase gathers one 16B load per lane per pair.
// Also zeroes out[n, h*16 .. h*16+16) so the separate memset dispatch is gone.
__global__ __launch_bounds__(256) void qkv_kernel(
    const float* __restrict__ x,    // (N, 64)
    const float* __restrict__ Wq,   // (4, 16, 16)
    const float* __restrict__ Wk,
    const float* __restrict__ Wv,
    float* __restrict__ q,          // (N, 64) fp32
    __half* __restrict__ kv,        // (N, 128) fp16 interleaved
    float* __restrict__ out)        // (N, 64) zero-filled here
{
    __shared__ float sWq[HH][DD * DD + 8];
    __shared__ float sWk[HH][DD * DD + 8];
    __shared__ float sWv[HH][DD * DD + 8];
    for (int t = threadIdx.x; t < HH * DD * DD; t += 256) {
        sWq[t >> 8][t & 255] = Wq[t];
        sWk[t >> 8][t & 255] = Wk[t];
        sWv[t >> 8][t & 255] = Wv[t];
    }
    __syncthreads();

    int gid = blockIdx.x * 256 + threadIdx.x;
    int n = gid >> 2;
    int h = gid & 3;
    if (n >= N_NODES_C) return;

    // x is a use-once stream -> nontemporal, keep caches for the kv/q tables
    const vf4* xp4 = reinterpret_cast<const vf4*>(x + (int64_t)n * FDIM + h * DD);
    float xr[DD];
#pragma unroll
    for (int d0 = 0; d0 < 4; d0++) {
        vf4 t4 = __builtin_nontemporal_load(xp4 + d0);
        xr[d0 * 4 + 0] = t4.x; xr[d0 * 4 + 1] = t4.y;
        xr[d0 * 4 + 2] = t4.z; xr[d0 * 4 + 3] = t4.w;
    }

    float qo[DD], ko[DD], vo[DD];
#pragma unroll
    for (int e = 0; e < DD; e++) { qo[e] = 0.f; ko[e] = 0.f; vo[e] = 0.f; }

    const float* wqh = sWq[h];
    const float* wkh = sWk[h];
    const float* wvh = sWv[h];
#pragma unroll
    for (int d = 0; d < DD; d++) {
        float xv = xr[d];
#pragma unroll
        for (int e = 0; e < DD; e++) {
            qo[e] = fmaf(xv, wqh[d * DD + e], qo[e]);
            ko[e] = fmaf(xv, wkh[d * DD + e], ko[e]);
            vo[e] = fmaf(xv, wvh[d * DD + e], vo[e]);
        }
    }

    int64_t qbase = (int64_t)n * FDIM + h * DD;
    float4 z4 = make_float4(0.f, 0.f, 0.f, 0.f);
#pragma unroll
    for (int e0 = 0; e0 < DD; e0 += 4) {
        *reinterpret_cast<float4*>(q + qbase + e0) =
            make_float4(qo[e0], qo[e0+1], qo[e0+2], qo[e0+3]);
        *reinterpret_cast<float4*>(out + qbase + e0) = z4;   // fused zero-fill
    }

    // interleaved fp16 kv row: 32 halves = 64 B per (n,h), 16B-aligned
    __half2 kvh[DD];
#pragma unroll
    for (int e = 0; e < DD; e++) kvh[e] = __floats2half2_rn(ko[e], vo[e]);
    uint4* dst = reinterpret_cast<uint4*>(kv + (int64_t)n * 128 + h * 32);
    const uint4* src = reinterpret_cast<const uint4*>(kvh);
#pragma unroll
    for (int t = 0; t < 4; t++) dst[t] = src[t];
}

// ---------------- Phase 2: per-pair attention + segmented scatter ----------------
// One 16-lane group per contiguous pair chunk; lane m owns float4 m of the
// 64-float row (head h = m>>2).
// Pipeline: w_ij (NT/HBM, ~900cy latency) prefetched 2 iterations deep —
// possible with no extra index state since w is indexed by p, not by j.
// kv gather (LLC-resident, ~400-600cy) stays 1 deep. Indices/scales 2 deep.
// All loop offsets are 32-bit shifts (strides are powers of two; buffers <4GB)
// to stay under the 64-VGPR occupancy cliff.
__global__ __launch_bounds__(256) void pair_kernel(
    const float* __restrict__ q,      // (N, 64) fp32
    const __half* __restrict__ kv,    // (N, 128) fp16 interleaved
    const float* __restrict__ w_ij,   // (P, 64)
    const float* __restrict__ phi,    // (P,)
    const float* __restrict__ mask,   // (P,)
    const int*  __restrict__ idx_i,   // (P,)
    const int*  __restrict__ idx_j,   // (P,)
    float* __restrict__ out,          // (N, 64)
    int pairs_per_group)
{
    int gid = blockIdx.x * 256 + threadIdx.x;
    int grp = gid >> 4;
    int m   = threadIdx.x & 15;

    int start = grp * pairs_per_group;        // < 1.6M, fits int32
    if (start >= N_PAIRS_C) return;
    int end = start + pairs_per_group;
    if (end > N_PAIRS_C) end = N_PAIRS_C;

    const vf4*    w4p  = reinterpret_cast<const vf4*>(w_ij);
    const float4* q4p  = reinterpret_cast<const float4*>(q);
    const uint4*  kv4p = reinterpret_cast<const uint4*>(kv);

    // ---- pipeline preload ----
    int p1 = (start + 1 < end) ? start + 1 : end - 1;
    int   i_a = __builtin_nontemporal_load(idx_i + start);
    int   j_a = __builtin_nontemporal_load(idx_j + start);
    float s_a = __builtin_nontemporal_load(phi + start)
              * __builtin_nontemporal_load(mask + start) * 0.25f;  // 1/sqrt(16) folded
    int   i_b = __builtin_nontemporal_load(idx_i + p1);
    int   j_b = __builtin_nontemporal_load(idx_j + p1);
    float s_b = __builtin_nontemporal_load(phi + p1)
              * __builtin_nontemporal_load(mask + p1) * 0.25f;

    vf4   w_a  = __builtin_nontemporal_load(w4p + (((uint32_t)start) << 4) + m);
    vf4   w_b  = __builtin_nontemporal_load(w4p + (((uint32_t)p1)    << 4) + m);
    uint4 kv_a = kv4p[(((uint32_t)j_a) << 4) + m];

    float4 q4  = q4p[(((uint32_t)i_a) << 4) + m];
    int cur_i  = i_a;
    float4 acc = make_float4(0.f, 0.f, 0.f, 0.f);

    for (int p = start; p < end; ++p) {
        int p2 = (p + 2 < end) ? p + 2 : end - 1;

        // incoming stage t+2: indices/scale + w payload (w needs no index)
        int   i_c = __builtin_nontemporal_load(idx_i + p2);
        int   j_c = __builtin_nontemporal_load(idx_j + p2);
        float s_c = __builtin_nontemporal_load(phi + p2)
                  * __builtin_nontemporal_load(mask + p2) * 0.25f;
        vf4   w_c = __builtin_nontemporal_load(w4p + (((uint32_t)p2) << 4) + m);

        // stage t+1 kv gather (j_b already resident -> no index wait)
        uint4 kv_b = kv4p[(((uint32_t)j_b) << 4) + m];

        // ---- compute stage t ----
        if (i_a != cur_i) {            // uniform within the 16-lane group
            uint32_t ob = (((uint32_t)cur_i) << 6) + (m << 2);
            atomicAdd(&out[ob + 0], acc.x);
            atomicAdd(&out[ob + 1], acc.y);
            atomicAdd(&out[ob + 2], acc.z);
            atomicAdd(&out[ob + 3], acc.w);
            acc = make_float4(0.f, 0.f, 0.f, 0.f);
            q4 = q4p[(((uint32_t)i_a) << 4) + m];
            cur_i = i_a;
        }

        const __half2* hp = reinterpret_cast<const __half2*>(&kv_a);
        float2 e0 = __half22float2(hp[0]);   // (k0, v0)
        float2 e1 = __half22float2(hp[1]);
        float2 e2 = __half22float2(hp[2]);
        float2 e3 = __half22float2(hp[3]);

        float r = q4.x * w_a.x * e0.x
                + q4.y * w_a.y * e1.x
                + q4.z * w_a.z * e2.x
                + q4.w * w_a.w * e3.x;
        // reduce across the 4 lanes of this head (lanes 4h..4h+3)
        r += __shfl_xor(r, 1);
        r += __shfl_xor(r, 2);
        float alpha = r * s_a;               // 0.25 pre-folded into s

        acc.x = fmaf(alpha, e0.y, acc.x);
        acc.y = fmaf(alpha, e1.y, acc.y);
        acc.z = fmaf(alpha, e2.y, acc.z);
        acc.w = fmaf(alpha, e3.y, acc.w);

        // rotate pipeline
        i_a = i_b; j_a = j_b; s_a = s_b;
        i_b = i_c; j_b = j_c; s_b = s_c;
        w_a = w_b; w_b = w_c; kv_a = kv_b;
    }

    // final flush
    {
        uint32_t ob = (((uint32_t)cur_i) << 6) + (m << 2);
        atomicAdd(&out[ob + 0], acc.x);
        atomicAdd(&out[ob + 1], acc.y);
        atomicAdd(&out[ob + 2], acc.z);
        atomicAdd(&out[ob + 3], acc.w);
    }
}

extern "C" void kernel_launch(void* const* d_in, const int* in_sizes, int n_in,
                              void* d_out, int out_size, void* d_ws, size_t ws_size,
                              hipStream_t stream) {
    const float* x       = (const float*)d_in[0];
    const float* w_ij    = (const float*)d_in[1];
    const float* phi     = (const float*)d_in[2];
    const float* mask    = (const float*)d_in[3];
    const float* Wq      = (const float*)d_in[4];
    const float* Wk      = (const float*)d_in[5];
    const float* Wv      = (const float*)d_in[6];
    const int*   idx_i   = (const int*)d_in[7];
    const int*   idx_j   = (const int*)d_in[8];
    float* out = (float*)d_out;

    float*  q  = (float*)d_ws;                                   // 25.6 MB
    __half* kv = (__half*)(q + (int64_t)N_NODES_C * FDIM);       // 25.6 MB

    // out zero-fill is fused into qkv_kernel (no separate memset dispatch)
    int qkv_blocks = (N_NODES_C * HH + 255) / 256;
    qkv_kernel<<<qkv_blocks, 256, 0, stream>>>(x, Wq, Wk, Wv, q, kv, out);

    // 2048 blocks x 16 groups = 32768 groups, ~49 pairs each
    const int n_groups = 32768;
    int pairs_per_group = (N_PAIRS_C + n_groups - 1) / n_groups;  // 49
    pair_kernel<<<n_groups / 16, 256, 0, stream>>>(q, kv, w_ij, phi, mask,
                                                   idx_i, idx_j, out, pairs_per_group);
}

// Round 2
// 675.874 us; speedup vs baseline: 1.0985x; 1.0985x over previous
//
#include <hip/hip_runtime.h>
#include <hip/hip_fp16.h>
#include <stdint.h>

#define N_NODES_C 100000
#define N_PAIRS_C 1600000
#define FDIM 64
#define HH 4
#define DD 16

typedef float vf4 __attribute__((ext_vector_type(4)));

// ---------------- Phase 1: per-head QKV projection (+ fused out-zeroing) ----
// One thread per (n, h). q table stays fp32 (read rarely, sequentially).
// k,v packed into ONE fp16 table, element-interleaved: kv[n][e*2+0]=k_e,
// kv[n][e*2+1]=v_e  -> pair-phase gathers one 16B load per lane per pair.
// Also zeroes out[n, h*16 .. h*16+16) so the separate memset dispatch is gone.
__global__ __launch_bounds__(256) void qkv_kernel(
    const float* __restrict__ x,    // (N, 64)
    const float* __restrict__ Wq,   // (4, 16, 16)
    const float* __restrict__ Wk,
    const float* __restrict__ Wv,
    float* __restrict__ q,          // (N, 64) fp32
    __half* __restrict__ kv,        // (N, 128) fp16 interleaved
    float* __restrict__ out)        // (N, 64) zero-filled here
{
    __shared__ float sWq[HH][DD * DD + 8];
    __shared__ float sWk[HH][DD * DD + 8];
    __shared__ float sWv[HH][DD * DD + 8];
    for (int t = threadIdx.x; t < HH * DD * DD; t += 256) {
        sWq[t >> 8][t & 255] = Wq[t];
        sWk[t >> 8][t & 255] = Wk[t];
        sWv[t >> 8][t & 255] = Wv[t];
    }
    __syncthreads();

    int gid = blockIdx.x * 256 + threadIdx.x;
    int n = gid >> 2;
    int h = gid & 3;
    if (n >= N_NODES_C) return;

    // x is a use-once stream (no inter-thread reuse of these 64B) -> nontemporal
    const vf4* xp4 = reinterpret_cast<const vf4*>(x + (int64_t)n * FDIM + h * DD);
    float xr[DD];
#pragma unroll
    for (int d0 = 0; d0 < 4; d0++) {
        vf4 t4 = __builtin_nontemporal_load(xp4 + d0);
        xr[d0 * 4 + 0] = t4.x; xr[d0 * 4 + 1] = t4.y;
        xr[d0 * 4 + 2] = t4.z; xr[d0 * 4 + 3] = t4.w;
    }

    float qo[DD], ko[DD], vo[DD];
#pragma unroll
    for (int e = 0; e < DD; e++) { qo[e] = 0.f; ko[e] = 0.f; vo[e] = 0.f; }

    const float* wqh = sWq[h];
    const float* wkh = sWk[h];
    const float* wvh = sWv[h];
#pragma unroll
    for (int d = 0; d < DD; d++) {
        float xv = xr[d];
#pragma unroll
        for (int e = 0; e < DD; e++) {
            qo[e] = fmaf(xv, wqh[d * DD + e], qo[e]);
            ko[e] = fmaf(xv, wkh[d * DD + e], ko[e]);
            vo[e] = fmaf(xv, wvh[d * DD + e], vo[e]);
        }
    }

    int64_t qbase = (int64_t)n * FDIM + h * DD;
    float4 z4 = make_float4(0.f, 0.f, 0.f, 0.f);
#pragma unroll
    for (int e0 = 0; e0 < DD; e0 += 4) {
        *reinterpret_cast<float4*>(q + qbase + e0) =
            make_float4(qo[e0], qo[e0+1], qo[e0+2], qo[e0+3]);
        *reinterpret_cast<float4*>(out + qbase + e0) = z4;   // fused zero-fill
    }

    // interleaved fp16 kv row: 32 halves = 64 B per (n,h), 16B-aligned
    __half2 kvh[DD];
#pragma unroll
    for (int e = 0; e < DD; e++) kvh[e] = __floats2half2_rn(ko[e], vo[e]);
    uint4* dst = reinterpret_cast<uint4*>(kv + (int64_t)n * 128 + h * 32);
    const uint4* src = reinterpret_cast<const uint4*>(kvh);
#pragma unroll
    for (int t = 0; t < 4; t++) dst[t] = src[t];
}

// ---------------- Phase 2: per-pair attention + segmented scatter ----------------
// One 16-lane group per contiguous pair chunk; lane m owns float4 m of the
// 64-float row (head h = m>>2). Round-0 pipeline structure (proven 672 us):
// depth-2 on indices/scales, depth-1 on payloads (w via NT, kv gather).
// Deltas vs round-0: uint32 shift addressing (all buffers <4GB, pow2 strides)
// to cut VALU + VGPRs, and __launch_bounds__(256,8) to pin 8 waves/SIMD
// (VGPR<=64) -- the occupancy this latency-bound gather loop needs.
__global__ __launch_bounds__(256, 8) void pair_kernel(
    const float* __restrict__ q,      // (N, 64) fp32
    const __half* __restrict__ kv,    // (N, 128) fp16 interleaved
    const float* __restrict__ w_ij,   // (P, 64)
    const float* __restrict__ phi,    // (P,)
    const float* __restrict__ mask,   // (P,)
    const int*  __restrict__ idx_i,   // (P,)
    const int*  __restrict__ idx_j,   // (P,)
    float* __restrict__ out,          // (N, 64)
    int pairs_per_group)
{
    int gid = blockIdx.x * 256 + threadIdx.x;
    int grp = gid >> 4;
    int m   = threadIdx.x & 15;

    int start = grp * pairs_per_group;        // < 1.6M, fits int32
    if (start >= N_PAIRS_C) return;
    int end = start + pairs_per_group;
    if (end > N_PAIRS_C) end = N_PAIRS_C;

    const vf4*    w4p  = reinterpret_cast<const vf4*>(w_ij);
    const float4* q4p  = reinterpret_cast<const float4*>(q);
    const uint4*  kv4p = reinterpret_cast<const uint4*>(kv);

    // ---- pipeline preload: stage A = iteration t, stage B = t+1 ----
    int p1 = (start + 1 < end) ? start + 1 : end - 1;
    int   i_a = idx_i[start];
    int   j_a = idx_j[start];
    float s_a = phi[start] * mask[start];
    int   i_b = idx_i[p1];
    int   j_b = idx_j[p1];
    float s_b = phi[p1] * mask[p1];

    vf4   w_a  = __builtin_nontemporal_load(w4p + (((uint32_t)start) << 4) + m);
    uint4 kv_a = kv4p[(((uint32_t)j_a) << 4) + m];

    float4 q4  = q4p[(((uint32_t)i_a) << 4) + m];
    int cur_i  = i_a;
    float4 acc = make_float4(0.f, 0.f, 0.f, 0.f);

    for (int p = start; p < end; ++p) {
        // prefetch stage t+2 indices (clamped)
        int p2 = (p + 2 < end) ? p + 2 : end - 1;
        int   i_c = idx_i[p2];
        int   j_c = idx_j[p2];
        float s_c = phi[p2] * mask[p2];

        // stage t+1 payload loads (j_b already resident -> no index wait)
        int pn = (p + 1 < end) ? p + 1 : end - 1;
        vf4   w_b  = __builtin_nontemporal_load(w4p + (((uint32_t)pn) << 4) + m);
        uint4 kv_b = kv4p[(((uint32_t)j_b) << 4) + m];

        // ---- compute stage t ----
        if (i_a != cur_i) {            // uniform within the 16-lane group
            uint32_t ob = (((uint32_t)cur_i) << 6) + (m << 2);
            atomicAdd(&out[ob + 0], acc.x);
            atomicAdd(&out[ob + 1], acc.y);
            atomicAdd(&out[ob + 2], acc.z);
            atomicAdd(&out[ob + 3], acc.w);
            acc = make_float4(0.f, 0.f, 0.f, 0.f);
            q4 = q4p[(((uint32_t)i_a) << 4) + m];
            cur_i = i_a;
        }

        const __half2* hp = reinterpret_cast<const __half2*>(&kv_a);
        float2 e0 = __half22float2(hp[0]);   // (k0, v0)
        float2 e1 = __half22float2(hp[1]);
        float2 e2 = __half22float2(hp[2]);
        float2 e3 = __half22float2(hp[3]);

        float r = q4.x * w_a.x * e0.x
                + q4.y * w_a.y * e1.x
                + q4.z * w_a.z * e2.x
                + q4.w * w_a.w * e3.x;
        // reduce across the 4 lanes of this head (lanes 4h..4h+3)
        r += __shfl_xor(r, 1);
        r += __shfl_xor(r, 2);
        float alpha = r * 0.25f * s_a;   // 1/sqrt(16)

        acc.x = fmaf(alpha, e0.y, acc.x);
        acc.y = fmaf(alpha, e1.y, acc.y);
        acc.z = fmaf(alpha, e2.y, acc.z);
        acc.w = fmaf(alpha, e3.y, acc.w);

        // rotate pipeline
        i_a = i_b; j_a = j_b; s_a = s_b;
        w_a = w_b; kv_a = kv_b;
        i_b = i_c; j_b = j_c; s_b = s_c;
    }

    // final flush
    {
        uint32_t ob = (((uint32_t)cur_i) << 6) + (m << 2);
        atomicAdd(&out[ob + 0], acc.x);
        atomicAdd(&out[ob + 1], acc.y);
        atomicAdd(&out[ob + 2], acc.z);
        atomicAdd(&out[ob + 3], acc.w);
    }
}

extern "C" void kernel_launch(void* const* d_in, const int* in_sizes, int n_in,
                              void* d_out, int out_size, void* d_ws, size_t ws_size,
                              hipStream_t stream) {
    const float* x       = (const float*)d_in[0];
    const float* w_ij    = (const float*)d_in[1];
    const float* phi     = (const float*)d_in[2];
    const float* mask    = (const float*)d_in[3];
    const float* Wq      = (const float*)d_in[4];
    const float* Wk      = (const float*)d_in[5];
    const float* Wv      = (const float*)d_in[6];
    const int*   idx_i   = (const int*)d_in[7];
    const int*   idx_j   = (const int*)d_in[8];
    float* out = (float*)d_out;

    float*  q  = (float*)d_ws;                                   // 25.6 MB
    __half* kv = (__half*)(q + (int64_t)N_NODES_C * FDIM);       // 25.6 MB

    // out zero-fill is fused into qkv_kernel (no separate memset dispatch)
    int qkv_blocks = (N_NODES_C * HH + 255) / 256;
    qkv_kernel<<<qkv_blocks, 256, 0, stream>>>(x, Wq, Wk, Wv, q, kv, out);

    // 2048 blocks x 16 groups = 32768 groups, ~49 pairs each
    const int n_groups = 32768;
    int pairs_per_group = (N_PAIRS_C + n_groups - 1) / n_groups;  // 49
    pair_kernel<<<n_groups / 16, 256, 0, stream>>>(q, kv, w_ij, phi, mask,
                                                   idx_i, idx_j, out, pairs_per_group);
}